// Round 2
// baseline (368.560 us; speedup 1.0000x reference)
//
#include <hip/hip_runtime.h>
#include <stdint.h>

// Y = tanh(X @ W + b):  M=65536 (8*64*128), K=512, N=512, all fp32.
// bf16 MFMA (32x32x16), fp32 accumulate. 128x128 block tile, BK=64,
// 4 waves (2x2), wave tile 64x64 (2x2 frags of 32x32, acc = 4x f32x16).
// R2: __launch_bounds__(256,4) -> 4 blocks/CU resident (was 2). Latency-bound
// per rocprof (Occ 21.5%, MfmaUtil 8%, HBM 16%); doubling residency doubles
// inter-block overlap of the barrier-locked staging chain.

typedef short bf16x8 __attribute__((ext_vector_type(8)));
typedef float f32x16 __attribute__((ext_vector_type(16)));

#define KTOT 512
#define NTOT 512
#define BK   64

__device__ __forceinline__ uint32_t pk2(float a, float b) {
  uint16_t lo = __builtin_bit_cast(uint16_t, (__bf16)a);   // RNE
  uint16_t hi = __builtin_bit_cast(uint16_t, (__bf16)b);
  return (uint32_t)lo | ((uint32_t)hi << 16);
}

__device__ __forceinline__ float fast_tanh(float z) {
  // tanh(z) = 1 - 2/(exp(2z)+1); exp(2z) = exp2(z * 2*log2(e))
  float t = __builtin_amdgcn_exp2f(z * 2.8853900817779268f);
  return 1.0f - 2.0f * __builtin_amdgcn_rcpf(t + 1.0f);
}

struct Regs {
  float4 a0,a1,a2,a3,a4,a5,a6,a7;   // 32 fp32 of X (one K-step slice)
  float4 u0,u1,u2,u3;               // W row 2*kp   (16 n)
  float4 v0,v1,v2,v3;               // W row 2*kp+1 (16 n)
};

__global__ __launch_bounds__(256, 4)
void hotdd_kernel(const float* __restrict__ X, const float* __restrict__ W,
                  const float* __restrict__ Bv, float* __restrict__ Y) {
  __shared__ char Ab[128 * BK * 2];   // A tile  [m:128][k:64] bf16, swizzled
  __shared__ char Bb[128 * BK * 2];   // W tile^T [n:128][k:64] bf16, swizzled

  // XCD swizzle: d = a*32 + b*8 + c  ->  bm = a*8+c, bn = b.
  // The 4 bn-blocks sharing an X strip get dispatch indices {d, d+8, d+16, d+24}:
  // same XCD (round-robin), adjacent in time -> X re-reads hit that XCD's L2.
  const int d  = blockIdx.x;
  const int bm = ((d >> 5) << 3) | (d & 7);   // 0..511
  const int bn = (d >> 3) & 3;                // 0..3

  const int tid  = threadIdx.x;
  const int lane = tid & 63;
  const int wv   = tid >> 6;
  const int wr   = (wv >> 1) * 64;   // wave M offset in tile
  const int wc   = (wv & 1) * 64;    // wave N offset in tile
  const int lo5  = lane & 31;
  const int hi1  = lane >> 5;
  const int rs   = lo5 & 7;          // read-side swizzle key

  // ---- A staging map: thread -> (m = tid>>1, half ah of 64 k)
  const int am   = tid >> 1;
  const int ah   = tid & 1;
  const int amz  = am & 7;
  const int abase = am * 128;
  const float* Ag = X + (size_t)(bm * 128 + am) * KTOT + ah * 32;

  // ---- B staging map: lane kp=lo5 owns k = {2kp, 2kp+1}; 16 n per thread
  const int kp = lo5;
  const int ng = wv * 32 + hi1 * 16;               // local n base
  const float* Bg = W + (size_t)(2 * kp) * NTOT + bn * 128 + ng;

#define LOADR(R, K0) do {                                                     \
    const float* ap_ = Ag + (K0);                                             \
    R.a0 = *(const float4*)(ap_ +  0); R.a1 = *(const float4*)(ap_ +  4);     \
    R.a2 = *(const float4*)(ap_ +  8); R.a3 = *(const float4*)(ap_ + 12);     \
    R.a4 = *(const float4*)(ap_ + 16); R.a5 = *(const float4*)(ap_ + 20);     \
    R.a6 = *(const float4*)(ap_ + 24); R.a7 = *(const float4*)(ap_ + 28);     \
    const float* bp_ = Bg + (size_t)(K0) * NTOT;                              \
    R.u0 = *(const float4*)(bp_ +  0); R.u1 = *(const float4*)(bp_ +  4);     \
    R.u2 = *(const float4*)(bp_ +  8); R.u3 = *(const float4*)(bp_ + 12);     \
    R.v0 = *(const float4*)(bp_ + NTOT +  0); R.v1 = *(const float4*)(bp_ + NTOT +  4); \
    R.v2 = *(const float4*)(bp_ + NTOT +  8); R.v3 = *(const float4*)(bp_ + NTOT + 12); \
  } while (0)

  // A: 4x ds_write_b128, swizzled slot = (ah*4+j) ^ (am&7)
#define AST(R, J, P, Q)                                                       \
    *(uint4*)(Ab + abase + (((((ah << 2) + (J)) ^ amz)) << 4)) =              \
      make_uint4(pk2(R.P.x, R.P.y), pk2(R.P.z, R.P.w),                        \
                 pk2(R.Q.x, R.Q.y), pk2(R.Q.z, R.Q.w));
  // B: 16x ds_write_b32 (k-pair packed), banks spread by kp -> conflict-free
#define BST(R, I, UV, C)                                                      \
    *(uint32_t*)(Bb + (ng + (I)) * 128 + ((kp << 2) ^ (((I) & 7) << 4))) =    \
      pk2(R.u##UV.C, R.v##UV.C);

#define STORER(R) do {                                                        \
    AST(R, 0, a0, a1) AST(R, 1, a2, a3) AST(R, 2, a4, a5) AST(R, 3, a6, a7)   \
    BST(R, 0, 0, x) BST(R, 1, 0, y) BST(R, 2, 0, z) BST(R, 3, 0, w)           \
    BST(R, 4, 1, x) BST(R, 5, 1, y) BST(R, 6, 1, z) BST(R, 7, 1, w)           \
    BST(R, 8, 2, x) BST(R, 9, 2, y) BST(R,10, 2, z) BST(R,11, 2, w)           \
    BST(R,12, 3, x) BST(R,13, 3, y) BST(R,14, 3, z) BST(R,15, 3, w)           \
  } while (0)

  f32x16 acc00 = {}, acc01 = {}, acc10 = {}, acc11 = {};

  const char* Ard0 = Ab + (wr + lo5) * 128;
  const char* Ard1 = Ard0 + 32 * 128;
  const char* Brd0 = Bb + (wc + lo5) * 128;
  const char* Brd1 = Brd0 + 32 * 128;

#define MFMA_PHASE() do {                                                     \
    _Pragma("unroll")                                                         \
    for (int kk = 0; kk < 4; ++kk) {                                          \
      const int sb = ((((kk << 1) | hi1) ^ rs) << 4);                         \
      bf16x8 fa0 = *(const bf16x8*)(Ard0 + sb);                               \
      bf16x8 fa1 = *(const bf16x8*)(Ard1 + sb);                               \
      bf16x8 fb0 = *(const bf16x8*)(Brd0 + sb);                               \
      bf16x8 fb1 = *(const bf16x8*)(Brd1 + sb);                               \
      acc00 = __builtin_amdgcn_mfma_f32_32x32x16_bf16(fa0, fb0, acc00, 0,0,0);\
      acc01 = __builtin_amdgcn_mfma_f32_32x32x16_bf16(fa0, fb1, acc01, 0,0,0);\
      acc10 = __builtin_amdgcn_mfma_f32_32x32x16_bf16(fa1, fb0, acc10, 0,0,0);\
      acc11 = __builtin_amdgcn_mfma_f32_32x32x16_bf16(fa1, fb1, acc11, 0,0,0);\
    }                                                                         \
  } while (0)

  Regs r0, r1;
  LOADR(r0, 0);

#pragma unroll 1
  for (int s = 0; s < 8; s += 2) {
    STORER(r0);
    __syncthreads();
    LOADR(r1, (s + 1) * BK);        // prefetch overlaps MFMA below
    MFMA_PHASE();
    __syncthreads();
    STORER(r1);
    __syncthreads();
    if (s + 2 < 8) LOADR(r0, (s + 2) * BK);
    MFMA_PHASE();
    __syncthreads();
  }

  // ---- epilogue: bias + tanh + fp32 store
  const int gn0 = bn * 128 + wc + lo5;
  const int gn1 = gn0 + 32;
  const float bv0 = Bv[gn0];
  const float bv1 = Bv[gn1];

#define EPI(ACC, MI, GN, BVAL) do {                                           \
    _Pragma("unroll")                                                         \
    for (int r = 0; r < 16; ++r) {                                            \
      const int mloc = wr + (MI) * 32 + (hi1 << 2) + ((r >> 2) << 3) + (r & 3);\
      Y[(size_t)(bm * 128 + mloc) * NTOT + (GN)] = fast_tanh((ACC)[r] + (BVAL));\
    }                                                                         \
  } while (0)

  EPI(acc00, 0, gn0, bv0);
  EPI(acc01, 0, gn1, bv1);
  EPI(acc10, 1, gn0, bv0);
  EPI(acc11, 1, gn1, bv1);
}

extern "C" void kernel_launch(void* const* d_in, const int* in_sizes, int n_in,
                              void* d_out, int out_size, void* d_ws, size_t ws_size,
                              hipStream_t stream) {
  (void)in_sizes; (void)n_in; (void)out_size; (void)d_ws; (void)ws_size;
  const float* X = (const float*)d_in[0];
  const float* W = (const float*)d_in[1];
  const float* b = (const float*)d_in[2];
  float* Y = (float*)d_out;
  // grid: 512 M-blocks x 4 N-blocks = 2048
  hipLaunchKernelGGL(hotdd_kernel, dim3(2048), dim3(256), 0, stream, X, W, b, Y);
}

// Round 3
// 297.349 us; speedup vs baseline: 1.2395x; 1.2395x over previous
//
#include <hip/hip_runtime.h>
#include <stdint.h>

// Y = tanh(X @ W + b):  M=65536 (8*64*128), K=512, N=512, all fp32.
// bf16 MFMA (32x32x16), fp32 accumulate. 128x128 block tile, BK=64,
// 4 waves (2x2), wave tile 64x64 (2x2 frags of 32x32, acc = 4x f32x16).
// R3: __launch_bounds__(256,3). R2's (256,4) capped VGPR at 128 -> the
// 2x64-float prefetch Regs spilled to scratch (VGPR 64, WRITE_SIZE 790 MB).
// (256,3) caps at ~170 VGPR: holds R1's 116 regs spill-free while lifting
// residency 2 -> 3 blocks/CU (8 -> 12 waves/CU).

typedef short bf16x8 __attribute__((ext_vector_type(8)));
typedef float f32x16 __attribute__((ext_vector_type(16)));

#define KTOT 512
#define NTOT 512
#define BK   64

__device__ __forceinline__ uint32_t pk2(float a, float b) {
  uint16_t lo = __builtin_bit_cast(uint16_t, (__bf16)a);   // RNE
  uint16_t hi = __builtin_bit_cast(uint16_t, (__bf16)b);
  return (uint32_t)lo | ((uint32_t)hi << 16);
}

__device__ __forceinline__ float fast_tanh(float z) {
  // tanh(z) = 1 - 2/(exp(2z)+1); exp(2z) = exp2(z * 2*log2(e))
  float t = __builtin_amdgcn_exp2f(z * 2.8853900817779268f);
  return 1.0f - 2.0f * __builtin_amdgcn_rcpf(t + 1.0f);
}

struct Regs {
  float4 a0,a1,a2,a3,a4,a5,a6,a7;   // 32 fp32 of X (one K-step slice)
  float4 u0,u1,u2,u3;               // W row 2*kp   (16 n)
  float4 v0,v1,v2,v3;               // W row 2*kp+1 (16 n)
};

__global__ __launch_bounds__(256, 3)
void hotdd_kernel(const float* __restrict__ X, const float* __restrict__ W,
                  const float* __restrict__ Bv, float* __restrict__ Y) {
  __shared__ char Ab[128 * BK * 2];   // A tile  [m:128][k:64] bf16, swizzled
  __shared__ char Bb[128 * BK * 2];   // W tile^T [n:128][k:64] bf16, swizzled

  // XCD swizzle: d = a*32 + b*8 + c  ->  bm = a*8+c, bn = b.
  // The 4 bn-blocks sharing an X strip get dispatch indices {d, d+8, d+16, d+24}:
  // same XCD (round-robin), adjacent in time -> X re-reads hit that XCD's L2.
  const int d  = blockIdx.x;
  const int bm = ((d >> 5) << 3) | (d & 7);   // 0..511
  const int bn = (d >> 3) & 3;                // 0..3

  const int tid  = threadIdx.x;
  const int lane = tid & 63;
  const int wv   = tid >> 6;
  const int wr   = (wv >> 1) * 64;   // wave M offset in tile
  const int wc   = (wv & 1) * 64;    // wave N offset in tile
  const int lo5  = lane & 31;
  const int hi1  = lane >> 5;
  const int rs   = lo5 & 7;          // read-side swizzle key

  // ---- A staging map: thread -> (m = tid>>1, half ah of 64 k)
  const int am   = tid >> 1;
  const int ah   = tid & 1;
  const int amz  = am & 7;
  const int abase = am * 128;
  const float* Ag = X + (size_t)(bm * 128 + am) * KTOT + ah * 32;

  // ---- B staging map: lane kp=lo5 owns k = {2kp, 2kp+1}; 16 n per thread
  const int kp = lo5;
  const int ng = wv * 32 + hi1 * 16;               // local n base
  const float* Bg = W + (size_t)(2 * kp) * NTOT + bn * 128 + ng;

#define LOADR(R, K0) do {                                                     \
    const float* ap_ = Ag + (K0);                                             \
    R.a0 = *(const float4*)(ap_ +  0); R.a1 = *(const float4*)(ap_ +  4);     \
    R.a2 = *(const float4*)(ap_ +  8); R.a3 = *(const float4*)(ap_ + 12);     \
    R.a4 = *(const float4*)(ap_ + 16); R.a5 = *(const float4*)(ap_ + 20);     \
    R.a6 = *(const float4*)(ap_ + 24); R.a7 = *(const float4*)(ap_ + 28);     \
    const float* bp_ = Bg + (size_t)(K0) * NTOT;                              \
    R.u0 = *(const float4*)(bp_ +  0); R.u1 = *(const float4*)(bp_ +  4);     \
    R.u2 = *(const float4*)(bp_ +  8); R.u3 = *(const float4*)(bp_ + 12);     \
    R.v0 = *(const float4*)(bp_ + NTOT +  0); R.v1 = *(const float4*)(bp_ + NTOT +  4); \
    R.v2 = *(const float4*)(bp_ + NTOT +  8); R.v3 = *(const float4*)(bp_ + NTOT + 12); \
  } while (0)

  // A: 4x ds_write_b128, swizzled slot = (ah*4+j) ^ (am&7)
#define AST(R, J, P, Q)                                                       \
    *(uint4*)(Ab + abase + (((((ah << 2) + (J)) ^ amz)) << 4)) =              \
      make_uint4(pk2(R.P.x, R.P.y), pk2(R.P.z, R.P.w),                        \
                 pk2(R.Q.x, R.Q.y), pk2(R.Q.z, R.Q.w));
  // B: 16x ds_write_b32 (k-pair packed), banks spread by kp -> conflict-free
#define BST(R, I, UV, C)                                                      \
    *(uint32_t*)(Bb + (ng + (I)) * 128 + ((kp << 2) ^ (((I) & 7) << 4))) =    \
      pk2(R.u##UV.C, R.v##UV.C);

#define STORER(R) do {                                                        \
    AST(R, 0, a0, a1) AST(R, 1, a2, a3) AST(R, 2, a4, a5) AST(R, 3, a6, a7)   \
    BST(R, 0, 0, x) BST(R, 1, 0, y) BST(R, 2, 0, z) BST(R, 3, 0, w)           \
    BST(R, 4, 1, x) BST(R, 5, 1, y) BST(R, 6, 1, z) BST(R, 7, 1, w)           \
    BST(R, 8, 2, x) BST(R, 9, 2, y) BST(R,10, 2, z) BST(R,11, 2, w)           \
    BST(R,12, 3, x) BST(R,13, 3, y) BST(R,14, 3, z) BST(R,15, 3, w)           \
  } while (0)

  f32x16 acc00 = {}, acc01 = {}, acc10 = {}, acc11 = {};

  const char* Ard0 = Ab + (wr + lo5) * 128;
  const char* Ard1 = Ard0 + 32 * 128;
  const char* Brd0 = Bb + (wc + lo5) * 128;
  const char* Brd1 = Brd0 + 32 * 128;

#define MFMA_PHASE() do {                                                     \
    _Pragma("unroll")                                                         \
    for (int kk = 0; kk < 4; ++kk) {                                          \
      const int sb = ((((kk << 1) | hi1) ^ rs) << 4);                         \
      bf16x8 fa0 = *(const bf16x8*)(Ard0 + sb);                               \
      bf16x8 fa1 = *(const bf16x8*)(Ard1 + sb);                               \
      bf16x8 fb0 = *(const bf16x8*)(Brd0 + sb);                               \
      bf16x8 fb1 = *(const bf16x8*)(Brd1 + sb);                               \
      acc00 = __builtin_amdgcn_mfma_f32_32x32x16_bf16(fa0, fb0, acc00, 0,0,0);\
      acc01 = __builtin_amdgcn_mfma_f32_32x32x16_bf16(fa0, fb1, acc01, 0,0,0);\
      acc10 = __builtin_amdgcn_mfma_f32_32x32x16_bf16(fa1, fb0, acc10, 0,0,0);\
      acc11 = __builtin_amdgcn_mfma_f32_32x32x16_bf16(fa1, fb1, acc11, 0,0,0);\
    }                                                                         \
  } while (0)

  Regs r0, r1;
  LOADR(r0, 0);

#pragma unroll 1
  for (int s = 0; s < 8; s += 2) {
    STORER(r0);
    __syncthreads();
    LOADR(r1, (s + 1) * BK);        // prefetch overlaps MFMA below
    MFMA_PHASE();
    __syncthreads();
    STORER(r1);
    __syncthreads();
    if (s + 2 < 8) LOADR(r0, (s + 2) * BK);
    MFMA_PHASE();
    __syncthreads();
  }

  // ---- epilogue: bias + tanh + fp32 store
  const int gn0 = bn * 128 + wc + lo5;
  const int gn1 = gn0 + 32;
  const float bv0 = Bv[gn0];
  const float bv1 = Bv[gn1];

#define EPI(ACC, MI, GN, BVAL) do {                                           \
    _Pragma("unroll")                                                         \
    for (int r = 0; r < 16; ++r) {                                            \
      const int mloc = wr + (MI) * 32 + (hi1 << 2) + ((r >> 2) << 3) + (r & 3);\
      Y[(size_t)(bm * 128 + mloc) * NTOT + (GN)] = fast_tanh((ACC)[r] + (BVAL));\
    }                                                                         \
  } while (0)

  EPI(acc00, 0, gn0, bv0);
  EPI(acc01, 0, gn1, bv1);
  EPI(acc10, 1, gn0, bv0);
  EPI(acc11, 1, gn1, bv1);
}

extern "C" void kernel_launch(void* const* d_in, const int* in_sizes, int n_in,
                              void* d_out, int out_size, void* d_ws, size_t ws_size,
                              hipStream_t stream) {
  (void)in_sizes; (void)n_in; (void)out_size; (void)d_ws; (void)ws_size;
  const float* X = (const float*)d_in[0];
  const float* W = (const float*)d_in[1];
  const float* b = (const float*)d_in[2];
  float* Y = (float*)d_out;
  // grid: 512 M-blocks x 4 N-blocks = 2048
  hipLaunchKernelGGL(hotdd_kernel, dim3(2048), dim3(256), 0, stream, X, W, b, Y);
}

// Round 4
// 92.627 us; speedup vs baseline: 3.9790x; 3.2102x over previous
//
#include <hip/hip_runtime.h>
#include <stdint.h>

// Y = tanh(X @ W + b):  M=65536 (8*64*128), K=512, N=512, all fp32.
// R4: two-pass design.
//  Pass 1 (cvtX/cvtW): fp32 -> bf16, written to d_ws in the EXACT swizzled
//  LDS-image layout (16KB tiles [128 rows][8 chunks], chunk j at slot
//  j^(row&7)). W is also transposed to [n][k].
//  Pass 2 (hotdd_main): 128x128 tile GEMM, BK=64, 4 waves, mfma 32x32x16 bf16.
//  Staging is pure global_load_lds_dwordx4 (no VGPR round-trip, no cvt in
//  the hot loop) -> ~90 VGPR -> true 4 blocks/CU under __launch_bounds__(256,4).
//  R2/R3 lesson: register-staged prefetch (needs >128 VGPR) and >2 blocks/CU
//  are mutually exclusive; spills showed as WRITE_SIZE 503-790 MB.

typedef short bf16x8 __attribute__((ext_vector_type(8)));
typedef float f32x16 __attribute__((ext_vector_type(16)));

#define KTOT 512
#define NTOT 512
#define BK   64
#define TILE_BYTES 16384          // 128 rows * 64 bf16 * 2B
#define XB_BYTES   67108864ull    // 65536*512*2
#define WT_BYTES   524288ull      // 512*512*2
#define WS_NEEDED  (XB_BYTES + WT_BYTES)

typedef __attribute__((address_space(3))) uint8_t lds8;
typedef __attribute__((address_space(1))) const uint8_t glb8;

__device__ __forceinline__ uint32_t pk2(float a, float b) {
  uint16_t lo = __builtin_bit_cast(uint16_t, (__bf16)a);   // RNE
  uint16_t hi = __builtin_bit_cast(uint16_t, (__bf16)b);
  return (uint32_t)lo | ((uint32_t)hi << 16);
}

__device__ __forceinline__ float fast_tanh(float z) {
  float t = __builtin_amdgcn_exp2f(z * 2.8853900817779268f);
  return 1.0f - 2.0f * __builtin_amdgcn_rcpf(t + 1.0f);
}

// ---------------- pass 1a: X fp32 -> bf16 swizzled tile image ----------------
// c -> j(chunk 0..7), r(row 0..127), tsm = tm*8+ts (tile id). One 16B chunk out.
__global__ __launch_bounds__(256)
void cvtX_kernel(const float* __restrict__ X, uint8_t* __restrict__ Xb) {
  const int c   = blockIdx.x * 256 + threadIdx.x;     // 0..4194303
  const int j   = c & 7;
  const int r   = (c >> 3) & 127;
  const int tsm = c >> 10;                            // 0..4095
  const int ts  = tsm & 7;
  const int tm  = tsm >> 3;
  const float* src = X + (size_t)(tm * 128 + r) * KTOT + ts * 64 + j * 8;
  float4 p = *(const float4*)src;
  float4 q = *(const float4*)(src + 4);
  uint4 v = make_uint4(pk2(p.x, p.y), pk2(p.z, p.w), pk2(q.x, q.y), pk2(q.z, q.w));
  *(uint4*)(Xb + ((size_t)tsm << 14) + (r << 7) + ((j ^ (r & 7)) << 4)) = v;
}

// ------- pass 1b: W fp32 [k][n] -> bf16 transposed swizzled tile image -------
__global__ __launch_bounds__(256)
void cvtW_kernel(const float* __restrict__ W, uint8_t* __restrict__ Wt) {
  const int c   = blockIdx.x * 256 + threadIdx.x;     // 0..32767
  const int j   = c & 7;
  const int r   = (c >> 3) & 127;                     // local n
  const int tsn = c >> 10;                            // tn*8+ts, 0..31
  const int ts  = tsn & 7;
  const int tn  = tsn >> 3;
  const int n   = tn * 128 + r;
  const int k0  = ts * 64 + j * 8;
  float e[8];
#pragma unroll
  for (int i = 0; i < 8; ++i) e[i] = W[(size_t)(k0 + i) * NTOT + n];
  uint4 v = make_uint4(pk2(e[0], e[1]), pk2(e[2], e[3]), pk2(e[4], e[5]), pk2(e[6], e[7]));
  *(uint4*)(Wt + ((size_t)tsn << 14) + (r << 7) + ((j ^ (r & 7)) << 4)) = v;
}

// ---------------- pass 2: main GEMM + bias + tanh ----------------
__global__ __launch_bounds__(256, 4)
void hotdd_main(const uint8_t* __restrict__ Xb, const uint8_t* __restrict__ Wt,
                const float* __restrict__ Bv, float* __restrict__ Y) {
  __shared__ uint8_t Ab[TILE_BYTES];
  __shared__ uint8_t Bb[TILE_BYTES];

  // XCD swizzle: the 4 bn-blocks sharing an Xb strip land on the same XCD,
  // dispatch-adjacent -> Xb re-reads hit that XCD's L2.
  const int d  = blockIdx.x;
  const int bm = ((d >> 5) << 3) | (d & 7);   // 0..511
  const int bn = (d >> 3) & 3;                // 0..3

  const int tid  = threadIdx.x;
  const int lane = tid & 63;
  const int wv   = tid >> 6;
  const int wr   = (wv >> 1) * 64;
  const int wc   = (wv & 1) * 64;
  const int lo5  = lane & 31;
  const int hi1  = lane >> 5;
  const int rs   = lo5 & 7;

  // staging: ws image == LDS image, linear copy. wave wv owns bytes
  // [wv*4096, wv*4096+4096) in 4 chunks of 1KB (64 lanes x 16B).
  const uint8_t* Asrc = Xb + ((size_t)(bm * 8) << 14) + wv * 4096 + lane * 16;
  const uint8_t* Bsrc = Wt + ((size_t)(bn * 8) << 14) + wv * 4096 + lane * 16;
  uint8_t* Adst = Ab + wv * 4096;   // wave-uniform; HW adds lane*16
  uint8_t* Bdst = Bb + wv * 4096;

#define STAGE(S) do {                                                         \
    const uint8_t* as_ = Asrc + ((S) << 14);                                  \
    const uint8_t* bs_ = Bsrc + ((S) << 14);                                  \
    _Pragma("unroll")                                                         \
    for (int q = 0; q < 4; ++q) {                                             \
      __builtin_amdgcn_global_load_lds((glb8*)(as_ + q * 1024),               \
                                       (lds8*)(Adst + q * 1024), 16, 0, 0);   \
      __builtin_amdgcn_global_load_lds((glb8*)(bs_ + q * 1024),               \
                                       (lds8*)(Bdst + q * 1024), 16, 0, 0);   \
    }                                                                         \
  } while (0)

  f32x16 acc00 = {}, acc01 = {}, acc10 = {}, acc11 = {};

  const uint8_t* Ard0 = Ab + (wr + lo5) * 128;
  const uint8_t* Ard1 = Ard0 + 32 * 128;
  const uint8_t* Brd0 = Bb + (wc + lo5) * 128;
  const uint8_t* Brd1 = Brd0 + 32 * 128;

#define MFMA_PHASE() do {                                                     \
    _Pragma("unroll")                                                         \
    for (int kk = 0; kk < 4; ++kk) {                                          \
      const int sb = ((((kk << 1) | hi1) ^ rs) << 4);                         \
      bf16x8 fa0 = *(const bf16x8*)(Ard0 + sb);                               \
      bf16x8 fa1 = *(const bf16x8*)(Ard1 + sb);                               \
      bf16x8 fb0 = *(const bf16x8*)(Brd0 + sb);                               \
      bf16x8 fb1 = *(const bf16x8*)(Brd1 + sb);                               \
      acc00 = __builtin_amdgcn_mfma_f32_32x32x16_bf16(fa0, fb0, acc00, 0,0,0);\
      acc01 = __builtin_amdgcn_mfma_f32_32x32x16_bf16(fa0, fb1, acc01, 0,0,0);\
      acc10 = __builtin_amdgcn_mfma_f32_32x32x16_bf16(fa1, fb0, acc10, 0,0,0);\
      acc11 = __builtin_amdgcn_mfma_f32_32x32x16_bf16(fa1, fb1, acc11, 0,0,0);\
    }                                                                         \
  } while (0)

#pragma unroll 1
  for (int s = 0; s < 8; ++s) {
    STAGE(s);
    asm volatile("s_waitcnt vmcnt(0)" ::: "memory");
    __syncthreads();                 // all 32KB landed, all waves ready
    MFMA_PHASE();
    __syncthreads();                 // all reads done before next overwrite
  }

  const int gn0 = bn * 128 + wc + lo5;
  const int gn1 = gn0 + 32;
  const float bv0 = Bv[gn0];
  const float bv1 = Bv[gn1];

#define EPI(ACC, MI, GN, BVAL) do {                                           \
    _Pragma("unroll")                                                         \
    for (int r = 0; r < 16; ++r) {                                            \
      const int mloc = wr + (MI) * 32 + (hi1 << 2) + ((r >> 2) << 3) + (r & 3);\
      Y[(size_t)(bm * 128 + mloc) * NTOT + (GN)] = fast_tanh((ACC)[r] + (BVAL));\
    }                                                                         \
  } while (0)

  EPI(acc00, 0, gn0, bv0);
  EPI(acc01, 0, gn1, bv1);
  EPI(acc10, 1, gn0, bv0);
  EPI(acc11, 1, gn1, bv1);
}

// ---------------- fallback: R1 kernel (passed @146us), used if ws too small --
struct Regs {
  float4 a0,a1,a2,a3,a4,a5,a6,a7;
  float4 u0,u1,u2,u3;
  float4 v0,v1,v2,v3;
};

__global__ __launch_bounds__(256, 2)
void hotdd_fallback(const float* __restrict__ X, const float* __restrict__ W,
                    const float* __restrict__ Bv, float* __restrict__ Y) {
  __shared__ char Ab[128 * BK * 2];
  __shared__ char Bb[128 * BK * 2];
  const int d  = blockIdx.x;
  const int bm = ((d >> 5) << 3) | (d & 7);
  const int bn = (d >> 3) & 3;
  const int tid  = threadIdx.x;
  const int lane = tid & 63;
  const int wv   = tid >> 6;
  const int wr   = (wv >> 1) * 64;
  const int wc   = (wv & 1) * 64;
  const int lo5  = lane & 31;
  const int hi1  = lane >> 5;
  const int rs   = lo5 & 7;
  const int am   = tid >> 1;
  const int ah   = tid & 1;
  const int amz  = am & 7;
  const int abase = am * 128;
  const float* Ag = X + (size_t)(bm * 128 + am) * KTOT + ah * 32;
  const int kp = lo5;
  const int ng = wv * 32 + hi1 * 16;
  const float* Bg = W + (size_t)(2 * kp) * NTOT + bn * 128 + ng;

#define LOADR(R, K0) do {                                                     \
    const float* ap_ = Ag + (K0);                                             \
    R.a0 = *(const float4*)(ap_ +  0); R.a1 = *(const float4*)(ap_ +  4);     \
    R.a2 = *(const float4*)(ap_ +  8); R.a3 = *(const float4*)(ap_ + 12);     \
    R.a4 = *(const float4*)(ap_ + 16); R.a5 = *(const float4*)(ap_ + 20);     \
    R.a6 = *(const float4*)(ap_ + 24); R.a7 = *(const float4*)(ap_ + 28);     \
    const float* bp_ = Bg + (size_t)(K0) * NTOT;                              \
    R.u0 = *(const float4*)(bp_ +  0); R.u1 = *(const float4*)(bp_ +  4);     \
    R.u2 = *(const float4*)(bp_ +  8); R.u3 = *(const float4*)(bp_ + 12);     \
    R.v0 = *(const float4*)(bp_ + NTOT +  0); R.v1 = *(const float4*)(bp_ + NTOT +  4); \
    R.v2 = *(const float4*)(bp_ + NTOT +  8); R.v3 = *(const float4*)(bp_ + NTOT + 12); \
  } while (0)

#define AST(R, J, P, Q)                                                       \
    *(uint4*)(Ab + abase + (((((ah << 2) + (J)) ^ amz)) << 4)) =              \
      make_uint4(pk2(R.P.x, R.P.y), pk2(R.P.z, R.P.w),                        \
                 pk2(R.Q.x, R.Q.y), pk2(R.Q.z, R.Q.w));
#define BST(R, I, UV, C)                                                      \
    *(uint32_t*)(Bb + (ng + (I)) * 128 + ((kp << 2) ^ (((I) & 7) << 4))) =    \
      pk2(R.u##UV.C, R.v##UV.C);

#define STORER(R) do {                                                        \
    AST(R, 0, a0, a1) AST(R, 1, a2, a3) AST(R, 2, a4, a5) AST(R, 3, a6, a7)   \
    BST(R, 0, 0, x) BST(R, 1, 0, y) BST(R, 2, 0, z) BST(R, 3, 0, w)           \
    BST(R, 4, 1, x) BST(R, 5, 1, y) BST(R, 6, 1, z) BST(R, 7, 1, w)           \
    BST(R, 8, 2, x) BST(R, 9, 2, y) BST(R,10, 2, z) BST(R,11, 2, w)           \
    BST(R,12, 3, x) BST(R,13, 3, y) BST(R,14, 3, z) BST(R,15, 3, w)           \
  } while (0)

  f32x16 acc00 = {}, acc01 = {}, acc10 = {}, acc11 = {};
  const char* Ard0 = Ab + (wr + lo5) * 128;
  const char* Ard1 = Ard0 + 32 * 128;
  const char* Brd0 = Bb + (wc + lo5) * 128;
  const char* Brd1 = Brd0 + 32 * 128;

#define MFMA_PHASE_F() do {                                                   \
    _Pragma("unroll")                                                         \
    for (int kk = 0; kk < 4; ++kk) {                                          \
      const int sb = ((((kk << 1) | hi1) ^ rs) << 4);                         \
      bf16x8 fa0 = *(const bf16x8*)(Ard0 + sb);                               \
      bf16x8 fa1 = *(const bf16x8*)(Ard1 + sb);                               \
      bf16x8 fb0 = *(const bf16x8*)(Brd0 + sb);                               \
      bf16x8 fb1 = *(const bf16x8*)(Brd1 + sb);                               \
      acc00 = __builtin_amdgcn_mfma_f32_32x32x16_bf16(fa0, fb0, acc00, 0,0,0);\
      acc01 = __builtin_amdgcn_mfma_f32_32x32x16_bf16(fa0, fb1, acc01, 0,0,0);\
      acc10 = __builtin_amdgcn_mfma_f32_32x32x16_bf16(fa1, fb0, acc10, 0,0,0);\
      acc11 = __builtin_amdgcn_mfma_f32_32x32x16_bf16(fa1, fb1, acc11, 0,0,0);\
    }                                                                         \
  } while (0)

  Regs r0, r1;
  LOADR(r0, 0);
#pragma unroll 1
  for (int s = 0; s < 8; s += 2) {
    STORER(r0);
    __syncthreads();
    LOADR(r1, (s + 1) * BK);
    MFMA_PHASE_F();
    __syncthreads();
    STORER(r1);
    __syncthreads();
    if (s + 2 < 8) LOADR(r0, (s + 2) * BK);
    MFMA_PHASE_F();
    __syncthreads();
  }

  const int gn0 = bn * 128 + wc + lo5;
  const int gn1 = gn0 + 32;
  const float bv0 = Bv[gn0];
  const float bv1 = Bv[gn1];
  EPI(acc00, 0, gn0, bv0);
  EPI(acc01, 0, gn1, bv1);
  EPI(acc10, 1, gn0, bv0);
  EPI(acc11, 1, gn1, bv1);
}

extern "C" void kernel_launch(void* const* d_in, const int* in_sizes, int n_in,
                              void* d_out, int out_size, void* d_ws, size_t ws_size,
                              hipStream_t stream) {
  (void)in_sizes; (void)n_in; (void)out_size;
  const float* X = (const float*)d_in[0];
  const float* W = (const float*)d_in[1];
  const float* b = (const float*)d_in[2];
  float* Y = (float*)d_out;
  if (ws_size >= WS_NEEDED) {
    uint8_t* Xb = (uint8_t*)d_ws;
    uint8_t* Wt = Xb + XB_BYTES;
    hipLaunchKernelGGL(cvtX_kernel, dim3(16384), dim3(256), 0, stream, X, Xb);
    hipLaunchKernelGGL(cvtW_kernel, dim3(128),   dim3(256), 0, stream, W, Wt);
    hipLaunchKernelGGL(hotdd_main,  dim3(2048),  dim3(256), 0, stream, Xb, Wt, b, Y);
  } else {
    hipLaunchKernelGGL(hotdd_fallback, dim3(2048), dim3(256), 0, stream, X, W, b, Y);
  }
}